// Round 5
// baseline (16.723 us; speedup 1.0000x reference)
//
#include <hip/hip_runtime.h>
#include <math.h>

// FraudDetectionNet: per-2x2-patch 4-qubit circuit -> Z expectations -> linear -> sigmoid.
//
// Algebra (verified absmax=0.0 in round 4):
//  - CNOT(0,1) and CNOT(2,3) never couple pairs {q0,q1}x{q2,q3} -> state factorizes
//    into two independent 2-qubit registers (4-dim each) for the whole circuit.
//  - First two identical RY layers fold: RY(t)RY(t)=RY(2t) -> double-angle product init.
//  - CNOT = register rename (free). Measurement folds into
//    (p0-p3)(w0+w1) + (p1-p2)(w0-w1).
//
// Structure (round 5): ONE WAVE PER IMAGE, fully self-contained.
//  - thread l handles h-pair l (all 64) and h-pair 64+l (l<34): 98 pairs/image.
//  - all loads issue up-front (8 independent float4 loads max), ~320 VALU ops,
//    6-step wave butterfly, lane 0 does bias+sigmoid+store.
//  - NO LDS, NO __syncthreads, NO atomics. 256-thread block = 4 independent waves
//    = 4 images. grid = 2048 blocks = 8 blocks/CU = 32 waves/CU, single batch.

__device__ __forceinline__ float reg2(float t0, float t1, float w0, float w1) {
    // clip to [-1,1]; half-angle = t*pi/2 -> hw trig in revolutions r = t*0.25
    const float u0 = fminf(fmaxf(t0, -1.0f), 1.0f);
    const float u1 = fminf(fmaxf(t1, -1.0f), 1.0f);
    const float s0 = __builtin_amdgcn_sinf(u0 * 0.25f);
    const float c0 = __builtin_amdgcn_cosf(u0 * 0.25f);
    const float s1 = __builtin_amdgcn_sinf(u1 * 0.25f);
    const float c1 = __builtin_amdgcn_cosf(u1 * 0.25f);
    // double angles: cos(t*pi) = 1-2s^2, sin(t*pi) = 2sc
    const float c20 = fmaf(-2.0f * s0, s0, 1.0f);
    const float s20 = (s0 + s0) * c0;
    const float c21 = fmaf(-2.0f * s1, s1, 1.0f);
    const float s21 = (s1 + s1) * c1;

    // folded RY^2 product init followed by CNOT (A2<->A3 renamed):
    float A0 = c20 * c21, A1 = c20 * s21, A2 = s20 * s21, A3 = s20 * c21;

    // 2 x [RY(t) layer on both wires, CNOT]
    #pragma unroll
    for (int l = 0; l < 2; ++l) {
        const float n0 = c0 * A0 - s0 * A2;
        const float n2 = s0 * A0 + c0 * A2;
        const float n1 = c0 * A1 - s0 * A3;
        const float n3 = s0 * A1 + c0 * A3;
        A0 = c1 * n0 - s1 * n1;
        A1 = s1 * n0 + c1 * n1;
        A2 = c1 * n2 - s1 * n3;
        A3 = s1 * n2 + c1 * n3;
        const float tt = A2; A2 = A3; A3 = tt;   // CNOT rename
    }

    const float p0 = A0 * A0, p1 = A1 * A1, p2 = A2 * A2, p3 = A3 * A3;
    return (p0 - p3) * (w0 + w1) + (p1 - p2) * (w0 - w1);
}

__device__ __forceinline__ float hpair(const float4 ra, const float4 rb,
                                       const float4 wA, const float4 wB) {
    // two adjacent 2x2 patches: row-major pixels (ra = top row 4 px, rb = bottom)
    return reg2(ra.x, ra.y, wA.x, wA.y) + reg2(rb.x, rb.y, wA.z, wA.w)
         + reg2(ra.z, ra.w, wB.x, wB.y) + reg2(rb.z, rb.w, wB.z, wB.w);
}

__global__ __launch_bounds__(256) void fraud_kernel(
    const float* __restrict__ x,     // (B,1,28,28)
    const float* __restrict__ W,     // (784,1)
    const float* __restrict__ bias,  // (1,)
    float* __restrict__ out)         // (B,)
{
    const int tid  = threadIdx.x;
    const int lane = tid & 63;
    const unsigned img = blockIdx.x * 4u + (unsigned)(tid >> 6);  // wave -> image

    const float* ximg = x + (size_t)img * 784;

    // ---- h-pair #1: pp = lane (0..63) ----
    const unsigned i1  = (unsigned)lane / 7u;
    const unsigned jj1 = (unsigned)lane - i1 * 7u;
    const float* p1 = ximg + (2u * i1) * 28 + 4u * jj1;
    const float4 ra1 = *reinterpret_cast<const float4*>(p1);
    const float4 rb1 = *reinterpret_cast<const float4*>(p1 + 28);
    const float4 wA1 = *reinterpret_cast<const float4*>(W + 8u * (unsigned)lane);
    const float4 wB1 = *reinterpret_cast<const float4*>(W + 8u * (unsigned)lane + 4);

    float partial = hpair(ra1, rb1, wA1, wB1);

    // ---- h-pair #2: pp = 64 + lane (lane < 34) ----
    if (lane < 34) {
        const unsigned pp  = 64u + (unsigned)lane;
        const unsigned i2  = pp / 7u;
        const unsigned jj2 = pp - i2 * 7u;
        const float* p2 = ximg + (2u * i2) * 28 + 4u * jj2;
        const float4 ra2 = *reinterpret_cast<const float4*>(p2);
        const float4 rb2 = *reinterpret_cast<const float4*>(p2 + 28);
        const float4 wA2 = *reinterpret_cast<const float4*>(W + 8u * pp);
        const float4 wB2 = *reinterpret_cast<const float4*>(W + 8u * pp + 4);
        partial += hpair(ra2, rb2, wA2, wB2);
    }

    // pure wave butterfly; lane 0 finishes. No LDS, no syncthreads.
    #pragma unroll
    for (int off = 32; off > 0; off >>= 1)
        partial += __shfl_xor(partial, off, 64);

    if (lane == 0)
        out[img] = 1.0f / (1.0f + __expf(-(partial + bias[0])));
}

extern "C" void kernel_launch(void* const* d_in, const int* in_sizes, int n_in,
                              void* d_out, int out_size, void* d_ws, size_t ws_size,
                              hipStream_t stream) {
    const float* x    = (const float*)d_in[0];
    const float* W    = (const float*)d_in[1];
    const float* bias = (const float*)d_in[2];
    float* out = (float*)d_out;

    const int B = out_size;                      // 8192 images
    fraud_kernel<<<dim3(B / 4), dim3(256), 0, stream>>>(x, W, bias, out);
}

// Round 6
// 13.143 us; speedup vs baseline: 1.2724x; 1.2724x over previous
//
#include <hip/hip_runtime.h>
#include <math.h>

// FraudDetectionNet: per-2x2-patch 4-qubit circuit -> Z expectations -> linear -> sigmoid.
//
// Algebra (verified absmax=0.0, rounds 3-5):
//  - CNOT(0,1)/CNOT(2,3) never couple pairs {q0,q1}x{q2,q3} -> state factorizes into
//    two independent 2-qubit registers for the whole circuit.
//  - First two identical RY layers fold: RY(t)RY(t)=RY(2t) -> double-angle product init.
//  - CNOT = register rename. Measurement folds to (p0-p3)(w0+w1)+(p1-p2)(w0-w1).
//
// Round 6: round-4 structure (best, 15.4us: block=128 per image, thread = h-pair,
// wave butterfly + 2-slot LDS) + PACKED FP32: the thread's two patches are packed
// as .x/.y of float2 ext-vectors so the backend emits v_pk_{mul,add,fma}_f32,
// halving non-trig VALU issue (~230 -> ~120 slots/thread). Trig stays scalar.

typedef float v2f __attribute__((ext_vector_type(2)));

__device__ __forceinline__ v2f vfma(v2f a, v2f b, v2f c) {
    return __builtin_elementwise_fma(a, b, c);
}

// Two independent 2-qubit registers (one per patch), SIMD over .x/.y.
// t0,t1 = the two pixel angles; w0,w1 = their weights. Returns per-patch partial.
__device__ __forceinline__ v2f reg2v(v2f t0, v2f t1, v2f w0, v2f w1) {
    const v2f onep = {  1.0f,  1.0f };
    const v2f onen = { -1.0f, -1.0f };
    const v2f qtr  = {  0.25f, 0.25f };

    // clip to [-1,1], half-angle t*pi/2 -> hw trig in revolutions r = t*0.25
    t0 = __builtin_elementwise_min(__builtin_elementwise_max(t0, onen), onep);
    t1 = __builtin_elementwise_min(__builtin_elementwise_max(t1, onen), onep);
    const v2f r0 = t0 * qtr;
    const v2f r1 = t1 * qtr;

    v2f s0, c0, s1, c1;                       // scalar trig per component
    s0.x = __builtin_amdgcn_sinf(r0.x);  s0.y = __builtin_amdgcn_sinf(r0.y);
    c0.x = __builtin_amdgcn_cosf(r0.x);  c0.y = __builtin_amdgcn_cosf(r0.y);
    s1.x = __builtin_amdgcn_sinf(r1.x);  s1.y = __builtin_amdgcn_sinf(r1.y);
    c1.x = __builtin_amdgcn_cosf(r1.x);  c1.y = __builtin_amdgcn_cosf(r1.y);

    // double angles: cos(t*pi) = 1-2s^2, sin(t*pi) = 2sc
    const v2f tm0 = s0 + s0;
    const v2f tm1 = s1 + s1;
    const v2f c20 = vfma(-tm0, s0, onep);
    const v2f s20 = tm0 * c0;
    const v2f c21 = vfma(-tm1, s1, onep);
    const v2f s21 = tm1 * c1;

    // folded RY^2 product init followed by CNOT (A2<->A3 renamed):
    v2f A0 = c20 * c21, A1 = c20 * s21, A2 = s20 * s21, A3 = s20 * c21;

    // 2 x [RY(t) layer on both wires, CNOT]
    #pragma unroll
    for (int l = 0; l < 2; ++l) {
        const v2f n0 = vfma(c0, A0, -(s0 * A2));
        const v2f n2 = vfma(s0, A0,   c0 * A2);
        const v2f n1 = vfma(c0, A1, -(s0 * A3));
        const v2f n3 = vfma(s0, A1,   c0 * A3);
        A0 = vfma(c1, n0, -(s1 * n1));
        A1 = vfma(s1, n0,   c1 * n1);
        A2 = vfma(c1, n2, -(s1 * n3));
        A3 = vfma(s1, n2,   c1 * n3);
        const v2f tt = A2; A2 = A3; A3 = tt;   // CNOT rename
    }

    const v2f p0 = A0 * A0, p1 = A1 * A1, p2 = A2 * A2, p3 = A3 * A3;
    return (p0 - p3) * (w0 + w1) + (p1 - p2) * (w0 - w1);
}

__global__ __launch_bounds__(128) void fraud_kernel(
    const float* __restrict__ x,     // (B,1,28,28)
    const float* __restrict__ W,     // (784,1)
    const float* __restrict__ bias,  // (1,)
    float* __restrict__ out)         // (B,)
{
    const int tid = threadIdx.x;
    const unsigned img = blockIdx.x;

    const unsigned pp = (tid < 98) ? (unsigned)tid : 0u;  // h-pair index 0..97
    const unsigned i  = pp / 7u;                          // patch row 0..13
    const unsigned jj = pp - i * 7u;                      // pair col 0..6

    // two adjacent patches: rows 2i,2i+1, cols 4jj..4jj+3 (16B-aligned)
    const float* rowp = x + (size_t)img * 784 + (2u * i) * 28 + 4u * jj;
    const float4 ra = *reinterpret_cast<const float4*>(rowp);        // top row: A.t0 A.t1 B.t0 B.t1
    const float4 rb = *reinterpret_cast<const float4*>(rowp + 28);   // bottom:  A.t2 A.t3 B.t2 B.t3
    const float4 wA = *reinterpret_cast<const float4*>(W + 8u * pp);
    const float4 wB = *reinterpret_cast<const float4*>(W + 8u * pp + 4);

    // pack patch A in .x, patch B in .y
    // top-row register (wires 0,1):   pixels (ra.x,ra.y)|(ra.z,ra.w), weights (wA.x,wA.y)|(wB.x,wB.y)
    // bottom-row register (wires 2,3): pixels (rb.x,rb.y)|(rb.z,rb.w), weights (wA.z,wA.w)|(wB.z,wB.w)
    const v2f rT = reg2v(v2f{ra.x, ra.z}, v2f{ra.y, ra.w},
                         v2f{wA.x, wB.x}, v2f{wA.y, wB.y});
    const v2f rB = reg2v(v2f{rb.x, rb.z}, v2f{rb.y, rb.w},
                         v2f{wA.z, wB.z}, v2f{wA.w, wB.w});

    float partial = (rT.x + rB.x) + (rT.y + rB.y);
    if (tid >= 98) partial = 0.0f;

    // wave butterfly + 2-slot LDS combine
    #pragma unroll
    for (int off = 32; off > 0; off >>= 1)
        partial += __shfl_xor(partial, off, 64);

    __shared__ float red[2];
    if ((tid & 63) == 0) red[tid >> 6] = partial;
    __syncthreads();

    if (tid == 0) {
        const float v = red[0] + red[1] + bias[0];
        out[img] = 1.0f / (1.0f + __expf(-v));
    }
}

extern "C" void kernel_launch(void* const* d_in, const int* in_sizes, int n_in,
                              void* d_out, int out_size, void* d_ws, size_t ws_size,
                              hipStream_t stream) {
    const float* x    = (const float*)d_in[0];
    const float* W    = (const float*)d_in[1];
    const float* bias = (const float*)d_in[2];
    float* out = (float*)d_out;

    const int B = out_size;  // 8192
    fraud_kernel<<<dim3(B), dim3(128), 0, stream>>>(x, W, bias, out);
}

// Round 7
// 12.684 us; speedup vs baseline: 1.3185x; 1.0362x over previous
//
#include <hip/hip_runtime.h>
#include <math.h>

// FraudDetectionNet: per-2x2-patch 4-qubit circuit -> Z expectations -> linear -> sigmoid.
//
// Algebra (verified absmax=0.0, rounds 3-6):
//  - CNOT(0,1)/CNOT(2,3) never couple pairs {q0,q1}x{q2,q3} -> state factorizes into
//    two independent 2-qubit registers for the whole circuit.
//  - First two identical RY layers fold: RY(t)RY(t)=RY(2t) -> double-angle product init.
//  - CNOT = register rename. Measurement folds to (p0-p3)(w0+w1)+(p1-p2)(w0-w1).
//  - Two patches per thread packed as .x/.y of float2 ext-vectors -> v_pk_{mul,add,fma}_f32.
//
// Round 7: same per-thread work as round 6 (13.1us), but 4 images per 512-thread
// block -> 2048 workgroups instead of 8192. WG dispatch rate is a visible cost at
// this scale; everything else (loads, packed math, wave butterfly) unchanged.

typedef float v2f __attribute__((ext_vector_type(2)));

__device__ __forceinline__ v2f vfma(v2f a, v2f b, v2f c) {
    return __builtin_elementwise_fma(a, b, c);
}

// Two independent 2-qubit registers (one per patch), SIMD over .x/.y.
__device__ __forceinline__ v2f reg2v(v2f t0, v2f t1, v2f w0, v2f w1) {
    const v2f onep = {  1.0f,  1.0f };
    const v2f onen = { -1.0f, -1.0f };
    const v2f qtr  = {  0.25f, 0.25f };

    // clip to [-1,1], half-angle t*pi/2 -> hw trig in revolutions r = t*0.25
    t0 = __builtin_elementwise_min(__builtin_elementwise_max(t0, onen), onep);
    t1 = __builtin_elementwise_min(__builtin_elementwise_max(t1, onen), onep);
    const v2f r0 = t0 * qtr;
    const v2f r1 = t1 * qtr;

    v2f s0, c0, s1, c1;                       // scalar trig per component
    s0.x = __builtin_amdgcn_sinf(r0.x);  s0.y = __builtin_amdgcn_sinf(r0.y);
    c0.x = __builtin_amdgcn_cosf(r0.x);  c0.y = __builtin_amdgcn_cosf(r0.y);
    s1.x = __builtin_amdgcn_sinf(r1.x);  s1.y = __builtin_amdgcn_sinf(r1.y);
    c1.x = __builtin_amdgcn_cosf(r1.x);  c1.y = __builtin_amdgcn_cosf(r1.y);

    // double angles: cos(t*pi) = 1-2s^2, sin(t*pi) = 2sc
    const v2f tm0 = s0 + s0;
    const v2f tm1 = s1 + s1;
    const v2f c20 = vfma(-tm0, s0, onep);
    const v2f s20 = tm0 * c0;
    const v2f c21 = vfma(-tm1, s1, onep);
    const v2f s21 = tm1 * c1;

    // folded RY^2 product init followed by CNOT (A2<->A3 renamed):
    v2f A0 = c20 * c21, A1 = c20 * s21, A2 = s20 * s21, A3 = s20 * c21;

    // 2 x [RY(t) layer on both wires, CNOT]
    #pragma unroll
    for (int l = 0; l < 2; ++l) {
        const v2f n0 = vfma(c0, A0, -(s0 * A2));
        const v2f n2 = vfma(s0, A0,   c0 * A2);
        const v2f n1 = vfma(c0, A1, -(s0 * A3));
        const v2f n3 = vfma(s0, A1,   c0 * A3);
        A0 = vfma(c1, n0, -(s1 * n1));
        A1 = vfma(s1, n0,   c1 * n1);
        A2 = vfma(c1, n2, -(s1 * n3));
        A3 = vfma(s1, n2,   c1 * n3);
        const v2f tt = A2; A2 = A3; A3 = tt;   // CNOT rename
    }

    const v2f p0 = A0 * A0, p1 = A1 * A1, p2 = A2 * A2, p3 = A3 * A3;
    return (p0 - p3) * (w0 + w1) + (p1 - p2) * (w0 - w1);
}

__global__ __launch_bounds__(512) void fraud_kernel(
    const float* __restrict__ x,     // (B,1,28,28)
    const float* __restrict__ W,     // (784,1)
    const float* __restrict__ bias,  // (1,)
    float* __restrict__ out)         // (B,)
{
    const int tid = threadIdx.x;
    const int sub = tid >> 7;                 // image slot 0..3 within block
    const int t   = tid & 127;                // thread within image
    const unsigned img = blockIdx.x * 4u + (unsigned)sub;

    const unsigned pp = (t < 98) ? (unsigned)t : 0u;   // h-pair index 0..97
    const unsigned i  = pp / 7u;                       // patch row 0..13
    const unsigned jj = pp - i * 7u;                   // pair col 0..6

    // two adjacent patches: rows 2i,2i+1, cols 4jj..4jj+3 (16B-aligned)
    const float* rowp = x + (size_t)img * 784 + (2u * i) * 28 + 4u * jj;
    const float4 ra = *reinterpret_cast<const float4*>(rowp);        // top row: A.t0 A.t1 B.t0 B.t1
    const float4 rb = *reinterpret_cast<const float4*>(rowp + 28);   // bottom:  A.t2 A.t3 B.t2 B.t3
    const float4 wA = *reinterpret_cast<const float4*>(W + 8u * pp);
    const float4 wB = *reinterpret_cast<const float4*>(W + 8u * pp + 4);

    // patch A in .x, patch B in .y
    const v2f rT = reg2v(v2f{ra.x, ra.z}, v2f{ra.y, ra.w},
                         v2f{wA.x, wB.x}, v2f{wA.y, wB.y});
    const v2f rB = reg2v(v2f{rb.x, rb.z}, v2f{rb.y, rb.w},
                         v2f{wA.z, wB.z}, v2f{wA.w, wB.w});

    float partial = (rT.x + rB.x) + (rT.y + rB.y);
    if (t >= 98) partial = 0.0f;

    // wave butterfly + LDS combine (2 waves per image)
    #pragma unroll
    for (int off = 32; off > 0; off >>= 1)
        partial += __shfl_xor(partial, off, 64);

    __shared__ float red[8];
    if ((tid & 63) == 0) red[tid >> 6] = partial;
    __syncthreads();

    if (t == 0) {
        const float v = red[2 * sub] + red[2 * sub + 1] + bias[0];
        out[img] = 1.0f / (1.0f + __expf(-v));
    }
}

extern "C" void kernel_launch(void* const* d_in, const int* in_sizes, int n_in,
                              void* d_out, int out_size, void* d_ws, size_t ws_size,
                              hipStream_t stream) {
    const float* x    = (const float*)d_in[0];
    const float* W    = (const float*)d_in[1];
    const float* bias = (const float*)d_in[2];
    float* out = (float*)d_out;

    const int B = out_size;  // 8192
    fraud_kernel<<<dim3(B / 4), dim3(512), 0, stream>>>(x, W, bias, out);
}